// Round 6
// baseline (879.538 us; speedup 1.0000x reference)
//
#include <hip/hip_runtime.h>
#include <stdint.h>

// TreeLSTM fused, round 6: persistent software-pipelined streaming.
// R5 structure + continuous HBM pipeline: Uh/fc issued at tile start
// (consumed at tile end), next-tile x issued before epilogue, biases in LDS
// (out of the vmcnt stream). Issue order == consumption order so in-order
// vmcnt retirement never stalls a younger consumer on an older stream.

typedef __attribute__((ext_vector_type(8))) short bf16x8;
typedef __attribute__((ext_vector_type(4))) float f32x4;
typedef __attribute__((ext_vector_type(4))) float f4v;

#define N_ROWS 200000
#define TILES 6250      // N_ROWS / 32
#define GRID 256        // persistent, 1 block/CU

__device__ __forceinline__ short f2bf(float f) {
    union { float f; uint32_t u; } v; v.f = f;
    return (short)((v.u + 0x7fffu + ((v.u >> 16) & 1u)) >> 16);
}
__device__ __forceinline__ float fsig(float x) { return 1.0f / (1.0f + __expf(-x)); }
__device__ __forceinline__ float ftanh(float x) {
    float e = __expf(2.0f * x);
    return 1.0f - 2.0f / (e + 1.0f);
}
__device__ __forceinline__ bf16x8 pack8(f4v a, f4v b) {
    bf16x8 o;
    o[0] = f2bf(a.x); o[1] = f2bf(a.y); o[2] = f2bf(a.z); o[3] = f2bf(a.w);
    o[4] = f2bf(b.x); o[5] = f2bf(b.y); o[6] = f2bf(b.z); o[7] = f2bf(b.w);
    return o;
}

// Pack W (f32) -> bf16 fragments: unit U=(s*4+g)*8+ks holds 64 lanes x 16B.
// Lane l of unit U = A-frag for tile (slice s, gate g), K-step ks:
//   A[row = l&15 -> col C=s*16+row of gate g][k = ks*32+(l>>4)*8 + 0..7]
__global__ void pack_w(const float* __restrict__ W_iou,
                       const float* __restrict__ W_f,
                       short* __restrict__ wpk) {
    const int task = blockIdx.x * 256 + threadIdx.x;   // 0..32767
    const int l = task & 63, U = task >> 6;
    const int ks = U & 7, g = (U >> 3) & 3, s = U >> 5;
    const int r = l & 15, q = l >> 4;
    const int C = s * 16 + r;
    const float* wr = (g < 3) ? (W_iou + (size_t)(g * 256 + C) * 256)
                              : (W_f + (size_t)C * 256);
    const f4v* p = (const f4v*)(wr + ks * 32 + q * 8);
    *(bf16x8*)(wpk + (size_t)task * 8) = pack8(p[0], p[1]);
}

template<bool PK>
__global__ __launch_bounds__(512, 2)
void treelstm_main(const float* __restrict__ x,
                   const float* __restrict__ Uh,
                   const float* __restrict__ fc,
                   const float* __restrict__ W_iou,
                   const float* __restrict__ b_iou,
                   const float* __restrict__ W_f,
                   const float* __restrict__ b_f,
                   const short* __restrict__ wpk,
                   float* __restrict__ out) {
    __shared__ float blds[1024];        // [0:768) b_iou, [768:1024) b_f
    const int tid  = threadIdx.x;
    const int lane = tid & 63;
    const int w    = tid >> 6;          // wave 0..7 -> slices 2w, 2w+1
    const int q    = lane >> 4;
    const int bcol = lane & 15;
    for (int i = tid; i < 1024; i += 512)
        blds[i] = (i < 768) ? b_iou[i] : b_f[i - 768];
    __syncthreads();                    // the only barrier

    const bf16x8* wp = (const bf16x8*)wpk;
    float* out_h = out;
    float* out_c = out + (size_t)N_ROWS * 256;
    float* out_f = out + 2 * (size_t)N_ROWS * 256;

    f4v xa[16];
    auto LOADX = [&](int t, int kh) {
#pragma unroll
        for (int r2 = 0; r2 < 2; ++r2)
#pragma unroll
            for (int ks = 0; ks < 4; ++ks) {
                const float* xr = x + (size_t)(t * 32 + r2 * 16 + bcol) * 256
                                + kh * 128 + ks * 32 + q * 8;
                xa[(r2 * 4 + ks) * 2]     = *(const f4v*)xr;
                xa[(r2 * 4 + ks) * 2 + 1] = *(const f4v*)(xr + 4);
            }
    };

    LOADX(blockIdx.x, 0);               // prologue prefetch

    for (int t = blockIdx.x; t < TILES; t += GRID) {
        const int n0 = t * 32;

        // ---- issue streaming epilogue loads FIRST (retire during MFMA) ----
        f4v ui[2][2], uo[2][2], uu[2][2], fv[2][2];
#pragma unroll
        for (int r2 = 0; r2 < 2; ++r2)
#pragma unroll
            for (int z = 0; z < 2; ++z) {
                const int n  = n0 + r2 * 16 + bcol;
                const int kb = (2 * w + z) * 16 + q * 4;
                const float* uh = Uh + (size_t)n * 768 + kb;
                ui[r2][z] = __builtin_nontemporal_load((const f4v*)uh);
                uo[r2][z] = __builtin_nontemporal_load((const f4v*)(uh + 256));
                uu[r2][z] = __builtin_nontemporal_load((const f4v*)(uh + 512));
                fv[r2][z] = __builtin_nontemporal_load((const f4v*)(fc + (size_t)n * 256 + kb));
            }

        f32x4 acc[2][2][4];
#pragma unroll
        for (int a = 0; a < 2; ++a)
#pragma unroll
            for (int b = 0; b < 2; ++b)
#pragma unroll
                for (int g = 0; g < 4; ++g) acc[a][b][g] = (f32x4){0.f, 0.f, 0.f, 0.f};

        bf16x8 xf[8];
#pragma unroll
        for (int kh = 0; kh < 2; ++kh) {
            // pack current half (waits only on xa, the oldest vmem in flight)
#pragma unroll
            for (int i = 0; i < 8; ++i) xf[i] = pack8(xa[2 * i], xa[2 * i + 1]);
            if (kh == 0) LOADX(t, 1);   // x second half lands under kh0 MFMA
#pragma unroll
            for (int ks = 0; ks < 4; ++ks) {
                const int ksg = kh * 4 + ks;
                bf16x8 wf[2][4];
#pragma unroll
                for (int z = 0; z < 2; ++z)
#pragma unroll
                    for (int g = 0; g < 4; ++g) {
                        if constexpr (PK) {
                            wf[z][g] = wp[(size_t)((((2 * w + z) * 4 + g) * 8) + ksg) * 64 + lane];
                        } else {
                            const int C = (2 * w + z) * 16 + bcol;
                            const float* wr = (g < 3) ? (W_iou + (size_t)(g * 256 + C) * 256)
                                                      : (W_f + (size_t)C * 256);
                            const f4v* pw = (const f4v*)(wr + ksg * 32 + q * 8);
                            wf[z][g] = pack8(pw[0], pw[1]);
                        }
                    }
#pragma unroll
                for (int z = 0; z < 2; ++z)
#pragma unroll
                    for (int g = 0; g < 4; ++g)
#pragma unroll
                        for (int r2 = 0; r2 < 2; ++r2)
                            acc[r2][z][g] = __builtin_amdgcn_mfma_f32_16x16x32_bf16(
                                wf[z][g], xf[r2 * 4 + ks], acc[r2][z][g], 0, 0, 0);
            }
        }

        // next tile's x: issued before epilogue so it flies under VALU+stores
        if (t + GRID < TILES) LOADX(t + GRID, 0);

        // ---- lane-local epilogue; biases from LDS (lgkmcnt, no vmem drag) ----
#pragma unroll
        for (int r2 = 0; r2 < 2; ++r2) {
            const int n = n0 + r2 * 16 + bcol;
#pragma unroll
            for (int z = 0; z < 2; ++z) {
                const int kb = (2 * w + z) * 16 + q * 4;
                const f4v bi  = *(const f4v*)&blds[kb];
                const f4v bo  = *(const f4v*)&blds[256 + kb];
                const f4v bu  = *(const f4v*)&blds[512 + kb];
                const f4v bf4 = *(const f4v*)&blds[768 + kb];
                const f32x4 ai = acc[r2][z][0], ao = acc[r2][z][1];
                const f32x4 au = acc[r2][z][2], af = acc[r2][z][3];
                const f4v u0 = ui[r2][z], o0 = uo[r2][z], uu0 = uu[r2][z], f0 = fv[r2][z];
                f4v cc, hh, ff;
                cc.x = fsig(ai[0] + bi.x + u0.x) * ftanh(au[0] + bu.x + uu0.x) + f0.x;
                cc.y = fsig(ai[1] + bi.y + u0.y) * ftanh(au[1] + bu.y + uu0.y) + f0.y;
                cc.z = fsig(ai[2] + bi.z + u0.z) * ftanh(au[2] + bu.z + uu0.z) + f0.z;
                cc.w = fsig(ai[3] + bi.w + u0.w) * ftanh(au[3] + bu.w + uu0.w) + f0.w;
                hh.x = fsig(ao[0] + bo.x + o0.x) * ftanh(cc.x);
                hh.y = fsig(ao[1] + bo.y + o0.y) * ftanh(cc.y);
                hh.z = fsig(ao[2] + bo.z + o0.z) * ftanh(cc.z);
                hh.w = fsig(ao[3] + bo.w + o0.w) * ftanh(cc.w);
                ff.x = af[0] + bf4.x;
                ff.y = af[1] + bf4.y;
                ff.z = af[2] + bf4.z;
                ff.w = af[3] + bf4.w;
                const size_t oidx = (size_t)n * 256 + kb;
                __builtin_nontemporal_store(hh, (f4v*)(out_h + oidx));
                __builtin_nontemporal_store(cc, (f4v*)(out_c + oidx));
                __builtin_nontemporal_store(ff, (f4v*)(out_f + oidx));
            }
        }
    }
}

extern "C" void kernel_launch(void* const* d_in, const int* in_sizes, int n_in,
                              void* d_out, int out_size, void* d_ws, size_t ws_size,
                              hipStream_t stream) {
    const float* x     = (const float*)d_in[0];
    const float* Uh    = (const float*)d_in[1];
    const float* fc    = (const float*)d_in[2];
    const float* W_iou = (const float*)d_in[3];
    const float* b_iou = (const float*)d_in[4];
    const float* W_f   = (const float*)d_in[5];
    const float* b_f   = (const float*)d_in[6];
    float* out = (float*)d_out;
    short* wpk = (short*)d_ws;

    if (ws_size >= 512 * 1024) {
        pack_w<<<128, 256, 0, stream>>>(W_iou, W_f, wpk);
        treelstm_main<true><<<GRID, 512, 0, stream>>>(x, Uh, fc, W_iou, b_iou,
                                                      W_f, b_f, wpk, out);
    } else {
        treelstm_main<false><<<GRID, 512, 0, stream>>>(x, Uh, fc, W_iou, b_iou,
                                                       W_f, b_f, wpk, out);
    }
}

// Round 7
// 775.456 us; speedup vs baseline: 1.1342x; 1.1342x over previous
//
#include <hip/hip_runtime.h>
#include <stdint.h>

// TreeLSTM fused, round 7: R5's byte-minimal schedule, quartered blocks for TLP.
// Block = 256 threads (4 waves), 16 rows x half-width (8 slices, 2/wave).
// 25000 one-shot blocks -> 4-6 independent blocks/CU; independent phase overlap
// covers HBM latency (R5 had 1 block/CU -> 1/3 issue duty cycle).
// Swizzle keeps a row-tile's siblings on one XCD so x is HBM-fetched once.

typedef __attribute__((ext_vector_type(8))) short bf16x8;
typedef __attribute__((ext_vector_type(4))) float f32x4;
typedef __attribute__((ext_vector_type(4))) float f4v;

#define N_ROWS 200000
#define GRID 25000      // (N_ROWS/16) row-tiles * 2 half-width blocks
#define CPX 3125        // GRID / 8 XCDs

__device__ __forceinline__ short f2bf(float f) {
    union { float f; uint32_t u; } v; v.f = f;
    return (short)((v.u + 0x7fffu + ((v.u >> 16) & 1u)) >> 16);
}
__device__ __forceinline__ float fsig(float x) { return 1.0f / (1.0f + __expf(-x)); }
__device__ __forceinline__ float ftanh(float x) {
    float e = __expf(2.0f * x);
    return 1.0f - 2.0f / (e + 1.0f);
}
__device__ __forceinline__ bf16x8 pack8(f4v a, f4v b) {
    bf16x8 o;
    o[0] = f2bf(a.x); o[1] = f2bf(a.y); o[2] = f2bf(a.z); o[3] = f2bf(a.w);
    o[4] = f2bf(b.x); o[5] = f2bf(b.y); o[6] = f2bf(b.z); o[7] = f2bf(b.w);
    return o;
}

// Pack W (f32) -> bf16 fragments: unit U=(s*4+g)*8+ks holds 64 lanes x 16B.
// Lane l of unit U = A-frag for tile (slice s, gate g), K-step ks:
//   A[row = l&15 -> col C=s*16+row of gate g][k = ks*32+(l>>4)*8 + 0..7]
__global__ void pack_w(const float* __restrict__ W_iou,
                       const float* __restrict__ W_f,
                       short* __restrict__ wpk) {
    const int task = blockIdx.x * 256 + threadIdx.x;   // 0..32767
    const int l = task & 63, U = task >> 6;
    const int ks = U & 7, g = (U >> 3) & 3, s = U >> 5;
    const int r = l & 15, q = l >> 4;
    const int C = s * 16 + r;
    const float* wr = (g < 3) ? (W_iou + (size_t)(g * 256 + C) * 256)
                              : (W_f + (size_t)C * 256);
    const f4v* p = (const f4v*)(wr + ks * 32 + q * 8);
    *(bf16x8*)(wpk + (size_t)task * 8) = pack8(p[0], p[1]);
}

template<bool PK>
__global__ __launch_bounds__(256, 4)
void treelstm_main(const float* __restrict__ x,
                   const float* __restrict__ Uh,
                   const float* __restrict__ fc,
                   const float* __restrict__ W_iou,
                   const float* __restrict__ b_iou,
                   const float* __restrict__ W_f,
                   const float* __restrict__ b_f,
                   const short* __restrict__ wpk,
                   float* __restrict__ out) {
    const int tid  = threadIdx.x;
    const int lane = tid & 63;
    const int w    = tid >> 6;          // wave 0..3
    const int q    = lane >> 4;
    const int bcol = lane & 15;

    // bijective swizzle: work id p; p=2k,2k+1 (same row-tile) share an XCD
    const int bid  = blockIdx.x;
    const int p    = (bid & 7) * CPX + (bid >> 3);
    const int rt   = p >> 1;            // row-tile 0..12499
    const int half = p & 1;             // width half
    const int n    = rt * 16 + bcol;    // this lane's row (exact)

    const bf16x8* wp = (const bf16x8*)wpk;
    float* out_h = out;
    float* out_c = out + (size_t)N_ROWS * 256;
    float* out_f = out + 2 * (size_t)N_ROWS * 256;

    // ---- x fragments: 8 coalesced dwordx4 in flight per half ----
    f4v xa[8];
    const float* xbase = x + (size_t)n * 256 + q * 8;
#pragma unroll
    for (int ks = 0; ks < 4; ++ks) {
        xa[2 * ks]     = *(const f4v*)(xbase + ks * 32);
        xa[2 * ks + 1] = *(const f4v*)(xbase + ks * 32 + 4);
    }

    f32x4 acc[2][4];                    // [z][gate]
#pragma unroll
    for (int z = 0; z < 2; ++z)
#pragma unroll
        for (int g = 0; g < 4; ++g) acc[z][g] = (f32x4){0.f, 0.f, 0.f, 0.f};

    bf16x8 xf[4];
#pragma unroll
    for (int kh = 0; kh < 2; ++kh) {
#pragma unroll
        for (int i = 0; i < 4; ++i) xf[i] = pack8(xa[2 * i], xa[2 * i + 1]);
        if (kh == 0) {                  // second half lands under kh0 MFMA
#pragma unroll
            for (int ks = 0; ks < 4; ++ks) {
                xa[2 * ks]     = *(const f4v*)(xbase + 128 + ks * 32);
                xa[2 * ks + 1] = *(const f4v*)(xbase + 128 + ks * 32 + 4);
            }
        }
#pragma unroll
        for (int ks = 0; ks < 4; ++ks) {
            const int ksg = kh * 4 + ks;
            bf16x8 wf[2][4];
#pragma unroll
            for (int z = 0; z < 2; ++z) {
                const int sl = half * 8 + 2 * w + z;   // global slice 0..15
#pragma unroll
                for (int g = 0; g < 4; ++g) {
                    if constexpr (PK) {
                        wf[z][g] = wp[(size_t)(((sl * 4 + g) * 8) + ksg) * 64 + lane];
                    } else {
                        const int C = sl * 16 + bcol;
                        const float* wr = (g < 3) ? (W_iou + (size_t)(g * 256 + C) * 256)
                                                  : (W_f + (size_t)C * 256);
                        const f4v* pw = (const f4v*)(wr + ksg * 32 + q * 8);
                        wf[z][g] = pack8(pw[0], pw[1]);
                    }
                }
            }
#pragma unroll
            for (int z = 0; z < 2; ++z)
#pragma unroll
                for (int g = 0; g < 4; ++g)
                    acc[z][g] = __builtin_amdgcn_mfma_f32_16x16x32_bf16(
                        wf[z][g], xf[ks], acc[z][g], 0, 0, 0);
        }
    }

    // ---- lane-local epilogue: gate g at k = sl*16 + q*4 + r; nt streaming ----
#pragma unroll
    for (int z = 0; z < 2; ++z) {
        const int sl = half * 8 + 2 * w + z;
        const int kb = sl * 16 + q * 4;
        const f4v bi  = *(const f4v*)&b_iou[kb];
        const f4v bo  = *(const f4v*)&b_iou[256 + kb];
        const f4v bu  = *(const f4v*)&b_iou[512 + kb];
        const f4v bf4 = *(const f4v*)&b_f[kb];
        const float* uh = Uh + (size_t)n * 768 + kb;
        const f4v ui = __builtin_nontemporal_load((const f4v*)uh);
        const f4v uo = __builtin_nontemporal_load((const f4v*)(uh + 256));
        const f4v uu = __builtin_nontemporal_load((const f4v*)(uh + 512));
        const f4v fv = __builtin_nontemporal_load((const f4v*)(fc + (size_t)n * 256 + kb));
        const f32x4 ai = acc[z][0], ao = acc[z][1];
        const f32x4 au = acc[z][2], af = acc[z][3];
        f4v cc, hh, ff;
        cc.x = fsig(ai[0] + bi.x + ui.x) * ftanh(au[0] + bu.x + uu.x) + fv.x;
        cc.y = fsig(ai[1] + bi.y + ui.y) * ftanh(au[1] + bu.y + uu.y) + fv.y;
        cc.z = fsig(ai[2] + bi.z + ui.z) * ftanh(au[2] + bu.z + uu.z) + fv.z;
        cc.w = fsig(ai[3] + bi.w + ui.w) * ftanh(au[3] + bu.w + uu.w) + fv.w;
        hh.x = fsig(ao[0] + bo.x + uo.x) * ftanh(cc.x);
        hh.y = fsig(ao[1] + bo.y + uo.y) * ftanh(cc.y);
        hh.z = fsig(ao[2] + bo.z + uo.z) * ftanh(cc.z);
        hh.w = fsig(ao[3] + bo.w + uo.w) * ftanh(cc.w);
        ff.x = af[0] + bf4.x;
        ff.y = af[1] + bf4.y;
        ff.z = af[2] + bf4.z;
        ff.w = af[3] + bf4.w;
        const size_t oidx = (size_t)n * 256 + kb;
        __builtin_nontemporal_store(hh, (f4v*)(out_h + oidx));
        __builtin_nontemporal_store(cc, (f4v*)(out_c + oidx));
        __builtin_nontemporal_store(ff, (f4v*)(out_f + oidx));
    }
}

extern "C" void kernel_launch(void* const* d_in, const int* in_sizes, int n_in,
                              void* d_out, int out_size, void* d_ws, size_t ws_size,
                              hipStream_t stream) {
    const float* x     = (const float*)d_in[0];
    const float* Uh    = (const float*)d_in[1];
    const float* fc    = (const float*)d_in[2];
    const float* W_iou = (const float*)d_in[3];
    const float* b_iou = (const float*)d_in[4];
    const float* W_f   = (const float*)d_in[5];
    const float* b_f   = (const float*)d_in[6];
    float* out = (float*)d_out;
    short* wpk = (short*)d_ws;

    if (ws_size >= 512 * 1024) {
        pack_w<<<128, 256, 0, stream>>>(W_iou, W_f, wpk);
        treelstm_main<true><<<GRID, 256, 0, stream>>>(x, Uh, fc, W_iou, b_iou,
                                                      W_f, b_f, wpk, out);
    } else {
        treelstm_main<false><<<GRID, 256, 0, stream>>>(x, Uh, fc, W_iou, b_iou,
                                                       W_f, b_f, wpk, out);
    }
}

// Round 8
// 687.747 us; speedup vs baseline: 1.2789x; 1.1275x over previous
//
#include <hip/hip_runtime.h>
#include <hip/hip_bf16.h>
#include <stdint.h>

// TreeLSTM fused, round 8: deep upfront HBM batches + Uh folded into acc init.
// Block = 16 rows x full 1024 cols, 256 thr (4 waves x 4 slices), grid 12500.
// Issue order == consumption order: x(kh0), Uh->acc, fc | pack | x(kh1) | pack
// | wf(L2)+MFMA (vmcnt never blocks on HBM) | reg-only epilogue + nt stores.
// launch_bounds(256,2): <=256 VGPR, 2 blocks/CU co-resident cover each other's
// load latency and epilogue tails.

typedef __attribute__((ext_vector_type(8))) short bf16x8;
typedef __attribute__((ext_vector_type(4))) float f4v;

#define N_ROWS 200000
#define GRID 12500      // N_ROWS / 16

__device__ __forceinline__ bf16x8 pack8(f4v a, f4v b) {
    union { __hip_bfloat162 h2[4]; bf16x8 v; } u;
    u.h2[0] = __float22bfloat162_rn(make_float2(a.x, a.y));
    u.h2[1] = __float22bfloat162_rn(make_float2(a.z, a.w));
    u.h2[2] = __float22bfloat162_rn(make_float2(b.x, b.y));
    u.h2[3] = __float22bfloat162_rn(make_float2(b.z, b.w));
    return u.v;
}
__device__ __forceinline__ float fsig(float x) { return 1.0f / (1.0f + __expf(-x)); }
__device__ __forceinline__ float ftanh(float x) {
    float e = __expf(2.0f * x);
    return 1.0f - 2.0f / (e + 1.0f);
}

// Pack W (f32) -> bf16 fragments: unit U=(s*4+g)*8+ks holds 64 lanes x 16B.
// Lane l of unit U = A-frag for tile (slice s, gate g), K-step ks:
//   A[row = l&15 -> col C=s*16+row of gate g][k = ks*32+(l>>4)*8 + 0..7]
__global__ void pack_w(const float* __restrict__ W_iou,
                       const float* __restrict__ W_f,
                       short* __restrict__ wpk) {
    const int task = blockIdx.x * 256 + threadIdx.x;   // 0..32767
    const int l = task & 63, U = task >> 6;
    const int ks = U & 7, g = (U >> 3) & 3, s = U >> 5;
    const int r = l & 15, q = l >> 4;
    const int C = s * 16 + r;
    const float* wr = (g < 3) ? (W_iou + (size_t)(g * 256 + C) * 256)
                              : (W_f + (size_t)C * 256);
    const f4v* p = (const f4v*)(wr + ks * 32 + q * 8);
    *(bf16x8*)(wpk + (size_t)task * 8) = pack8(p[0], p[1]);
}

template<bool PK>
__global__ __launch_bounds__(256, 2)
void treelstm_main(const float* __restrict__ x,
                   const float* __restrict__ Uh,
                   const float* __restrict__ fc,
                   const float* __restrict__ W_iou,
                   const float* __restrict__ b_iou,
                   const float* __restrict__ W_f,
                   const float* __restrict__ b_f,
                   const short* __restrict__ wpk,
                   float* __restrict__ out) {
    const int tid  = threadIdx.x;
    const int lane = tid & 63;
    const int w    = tid >> 6;          // wave 0..3 -> slices 4w..4w+3
    const int q    = lane >> 4;
    const int bcol = lane & 15;
    const int n    = blockIdx.x * 16 + bcol;   // this lane's row (exact)

    const bf16x8* wp = (const bf16x8*)wpk;
    float* out_h = out;
    float* out_c = out + (size_t)N_ROWS * 256;
    float* out_f = out + 2 * (size_t)N_ROWS * 256;

    // ---- phase 1: issue x(kh0) ----
    const float* xb = x + (size_t)n * 256 + q * 8;
    f4v xa[8];
#pragma unroll
    for (int ks = 0; ks < 4; ++ks) {
        xa[2 * ks]     = *(const f4v*)(xb + ks * 32);
        xa[2 * ks + 1] = *(const f4v*)(xb + ks * 32 + 4);
    }

    // ---- phase 2: issue Uh directly into accumulators, then fc ----
    f4v acc[4][4];                      // [z][gate]; D row=(q*4+r)->k, col=n
    f4v fcv[4];
#pragma unroll
    for (int z = 0; z < 4; ++z) {
        const int kb = (w * 4 + z) * 16 + q * 4;
        const float* uh = Uh + (size_t)n * 768 + kb;
        acc[z][0] = __builtin_nontemporal_load((const f4v*)uh);
        acc[z][1] = __builtin_nontemporal_load((const f4v*)(uh + 256));
        acc[z][2] = __builtin_nontemporal_load((const f4v*)(uh + 512));
        acc[z][3] = (f4v){0.f, 0.f, 0.f, 0.f};
    }
#pragma unroll
    for (int z = 0; z < 4; ++z) {
        const int kb = (w * 4 + z) * 16 + q * 4;
        fcv[z] = __builtin_nontemporal_load((const f4v*)(fc + (size_t)n * 256 + kb));
    }

    // ---- pack kh0 (waits only on x), then issue+pack kh1 ----
    bf16x8 xf[8];
#pragma unroll
    for (int i = 0; i < 4; ++i) xf[i] = pack8(xa[2 * i], xa[2 * i + 1]);
#pragma unroll
    for (int ks = 0; ks < 4; ++ks) {
        xa[2 * ks]     = *(const f4v*)(xb + 128 + ks * 32);
        xa[2 * ks + 1] = *(const f4v*)(xb + 128 + ks * 32 + 4);
    }
#pragma unroll
    for (int i = 0; i < 4; ++i) xf[4 + i] = pack8(xa[2 * i], xa[2 * i + 1]);

    // ---- MFMA loop: wf from packed L2 stream; no HBM load younger than these ----
#pragma unroll
    for (int ks = 0; ks < 8; ++ks) {
        bf16x8 wf[4][4];
#pragma unroll
        for (int z = 0; z < 4; ++z) {
            const int sl = w * 4 + z;
#pragma unroll
            for (int g = 0; g < 4; ++g) {
                if constexpr (PK) {
                    wf[z][g] = wp[(size_t)(((sl * 4 + g) * 8) + ks) * 64 + lane];
                } else {
                    const int C = sl * 16 + bcol;
                    const float* wr = (g < 3) ? (W_iou + (size_t)(g * 256 + C) * 256)
                                              : (W_f + (size_t)C * 256);
                    const f4v* pw = (const f4v*)(wr + ks * 32 + q * 8);
                    wf[z][g] = pack8(pw[0], pw[1]);
                }
            }
        }
#pragma unroll
        for (int z = 0; z < 4; ++z)
#pragma unroll
            for (int g = 0; g < 4; ++g)
                acc[z][g] = __builtin_amdgcn_mfma_f32_16x16x32_bf16(
                    wf[z][g], xf[ks], acc[z][g], 0, 0, 0);
    }

    // ---- epilogue: acc already includes Uh; add bias, gates, nt stores ----
#pragma unroll
    for (int z = 0; z < 4; ++z) {
        const int kb = (w * 4 + z) * 16 + q * 4;
        const f4v bi  = *(const f4v*)&b_iou[kb];
        const f4v bo  = *(const f4v*)&b_iou[256 + kb];
        const f4v bu  = *(const f4v*)&b_iou[512 + kb];
        const f4v bf4 = *(const f4v*)&b_f[kb];
        const f4v ai = acc[z][0], ao = acc[z][1], au = acc[z][2], af = acc[z][3];
        const f4v fv = fcv[z];
        f4v cc, hh, ff;
        cc.x = fsig(ai.x + bi.x) * ftanh(au.x + bu.x) + fv.x;
        cc.y = fsig(ai.y + bi.y) * ftanh(au.y + bu.y) + fv.y;
        cc.z = fsig(ai.z + bi.z) * ftanh(au.z + bu.z) + fv.z;
        cc.w = fsig(ai.w + bi.w) * ftanh(au.w + bu.w) + fv.w;
        hh.x = fsig(ao.x + bo.x) * ftanh(cc.x);
        hh.y = fsig(ao.y + bo.y) * ftanh(cc.y);
        hh.z = fsig(ao.z + bo.z) * ftanh(cc.z);
        hh.w = fsig(ao.w + bo.w) * ftanh(cc.w);
        ff.x = af.x + bf4.x;
        ff.y = af.y + bf4.y;
        ff.z = af.z + bf4.z;
        ff.w = af.w + bf4.w;
        const size_t oidx = (size_t)n * 256 + kb;
        __builtin_nontemporal_store(hh, (f4v*)(out_h + oidx));
        __builtin_nontemporal_store(cc, (f4v*)(out_c + oidx));
        __builtin_nontemporal_store(ff, (f4v*)(out_f + oidx));
    }
}

extern "C" void kernel_launch(void* const* d_in, const int* in_sizes, int n_in,
                              void* d_out, int out_size, void* d_ws, size_t ws_size,
                              hipStream_t stream) {
    const float* x     = (const float*)d_in[0];
    const float* Uh    = (const float*)d_in[1];
    const float* fc    = (const float*)d_in[2];
    const float* W_iou = (const float*)d_in[3];
    const float* b_iou = (const float*)d_in[4];
    const float* W_f   = (const float*)d_in[5];
    const float* b_f   = (const float*)d_in[6];
    float* out = (float*)d_out;
    short* wpk = (short*)d_ws;

    if (ws_size >= 512 * 1024) {
        pack_w<<<128, 256, 0, stream>>>(W_iou, W_f, wpk);
        treelstm_main<true><<<GRID, 256, 0, stream>>>(x, Uh, fc, W_iou, b_iou,
                                                      W_f, b_f, wpk, out);
    } else {
        treelstm_main<false><<<GRID, 256, 0, stream>>>(x, Uh, fc, W_iou, b_iou,
                                                       W_f, b_f, wpk, out);
    }
}

// Round 9
// 583.620 us; speedup vs baseline: 1.5070x; 1.1784x over previous
//
#include <hip/hip_runtime.h>
#include <hip/hip_bf16.h>
#include <stdint.h>

// TreeLSTM fused, round 9: R8 structure + sched_barrier(0) fences so the
// compiler cannot sink the upfront HBM load batches (R5/7/8 all collapsed to
// VGPR 60-80 => ~2 loads in flight => 2 TB/s). Pinned batches force ~200 VGPR
// live and 32 KB/wave in flight.
// Block = 16 rows x full 1024 cols, 256 thr (4 waves x 4 slices), grid 12500.

typedef __attribute__((ext_vector_type(8))) short bf16x8;
typedef __attribute__((ext_vector_type(4))) float f4v;

#define N_ROWS 200000
#define GRID 12500      // N_ROWS / 16
#define SBAR() __builtin_amdgcn_sched_barrier(0)

__device__ __forceinline__ bf16x8 pack8(f4v a, f4v b) {
    union { __hip_bfloat162 h2[4]; bf16x8 v; } u;
    u.h2[0] = __float22bfloat162_rn(make_float2(a.x, a.y));
    u.h2[1] = __float22bfloat162_rn(make_float2(a.z, a.w));
    u.h2[2] = __float22bfloat162_rn(make_float2(b.x, b.y));
    u.h2[3] = __float22bfloat162_rn(make_float2(b.z, b.w));
    return u.v;
}
__device__ __forceinline__ float fsig(float x) { return 1.0f / (1.0f + __expf(-x)); }
__device__ __forceinline__ float ftanh(float x) {
    float e = __expf(2.0f * x);
    return 1.0f - 2.0f / (e + 1.0f);
}

// Pack W (f32) -> bf16 fragments: unit U=(s*4+g)*8+ks holds 64 lanes x 16B.
// Lane l of unit U = A-frag for tile (slice s, gate g), K-step ks:
//   A[row = l&15 -> col C=s*16+row of gate g][k = ks*32+(l>>4)*8 + 0..7]
__global__ void pack_w(const float* __restrict__ W_iou,
                       const float* __restrict__ W_f,
                       short* __restrict__ wpk) {
    const int task = blockIdx.x * 256 + threadIdx.x;   // 0..32767
    const int l = task & 63, U = task >> 6;
    const int ks = U & 7, g = (U >> 3) & 3, s = U >> 5;
    const int r = l & 15, q = l >> 4;
    const int C = s * 16 + r;
    const float* wr = (g < 3) ? (W_iou + (size_t)(g * 256 + C) * 256)
                              : (W_f + (size_t)C * 256);
    const f4v* p = (const f4v*)(wr + ks * 32 + q * 8);
    *(bf16x8*)(wpk + (size_t)task * 8) = pack8(p[0], p[1]);
}

template<bool PK>
__global__ __launch_bounds__(256, 2)
void treelstm_main(const float* __restrict__ x,
                   const float* __restrict__ Uh,
                   const float* __restrict__ fc,
                   const float* __restrict__ W_iou,
                   const float* __restrict__ b_iou,
                   const float* __restrict__ W_f,
                   const float* __restrict__ b_f,
                   const short* __restrict__ wpk,
                   float* __restrict__ out) {
    const int tid  = threadIdx.x;
    const int lane = tid & 63;
    const int w    = tid >> 6;          // wave 0..3 -> slices 4w..4w+3
    const int q    = lane >> 4;
    const int bcol = lane & 15;
    const int n    = blockIdx.x * 16 + bcol;   // this lane's row (exact)

    const bf16x8* wp = (const bf16x8*)wpk;
    float* out_h = out;
    float* out_c = out + (size_t)N_ROWS * 256;
    float* out_f = out + 2 * (size_t)N_ROWS * 256;

    // ---- phase A (PINNED): issue x(kh0) then Uh->acc then fc; 32 VMEM ----
    const float* xb = x + (size_t)n * 256 + q * 8;
    f4v xa[8];
#pragma unroll
    for (int ks = 0; ks < 4; ++ks) {
        xa[2 * ks]     = *(const f4v*)(xb + ks * 32);
        xa[2 * ks + 1] = *(const f4v*)(xb + ks * 32 + 4);
    }
    f4v acc[4][4];                      // [z][gate]; D row=(q*4+r)->k, col=n
    f4v fcv[4];
#pragma unroll
    for (int z = 0; z < 4; ++z) {
        const int kb = (w * 4 + z) * 16 + q * 4;
        const float* uh = Uh + (size_t)n * 768 + kb;
        acc[z][0] = __builtin_nontemporal_load((const f4v*)uh);
        acc[z][1] = __builtin_nontemporal_load((const f4v*)(uh + 256));
        acc[z][2] = __builtin_nontemporal_load((const f4v*)(uh + 512));
        acc[z][3] = (f4v){0.f, 0.f, 0.f, 0.f};
        fcv[z] = __builtin_nontemporal_load((const f4v*)(fc + (size_t)n * 256 + kb));
    }
    SBAR();

    // ---- pack kh0: vmcnt waits x0 only; Uh/fc stay in flight ----
    bf16x8 xf[8];
#pragma unroll
    for (int i = 0; i < 4; ++i) xf[i] = pack8(xa[2 * i], xa[2 * i + 1]);
    SBAR();

    // ---- issue x(kh1) into same xa regs (PINNED) ----
#pragma unroll
    for (int ks = 0; ks < 4; ++ks) {
        xa[2 * ks]     = *(const f4v*)(xb + 128 + ks * 32);
        xa[2 * ks + 1] = *(const f4v*)(xb + 128 + ks * 32 + 4);
    }
    SBAR();
#pragma unroll
    for (int i = 0; i < 4; ++i) xf[4 + i] = pack8(xa[2 * i], xa[2 * i + 1]);
    SBAR();
    // in-order retirement: the pack-kh1 wait above also drained Uh/fc, so the
    // MFMA C-operand (acc = Uh) is ready with no further stall.

    // ---- MFMA loop: wf from packed L2 stream; compiler free to overlap ----
#pragma unroll
    for (int ks = 0; ks < 8; ++ks) {
        bf16x8 wf[16];
#pragma unroll
        for (int z = 0; z < 4; ++z) {
#pragma unroll
            for (int g = 0; g < 4; ++g) {
                if constexpr (PK) {
                    wf[z * 4 + g] = wp[(size_t)((((w * 4 + z) * 4 + g) * 8) + ks) * 64 + lane];
                } else {
                    const int C = (w * 4 + z) * 16 + bcol;
                    const float* wr = (g < 3) ? (W_iou + (size_t)(g * 256 + C) * 256)
                                              : (W_f + (size_t)C * 256);
                    const f4v* pw = (const f4v*)(wr + ks * 32 + q * 8);
                    wf[z * 4 + g] = pack8(pw[0], pw[1]);
                }
            }
        }
#pragma unroll
        for (int z = 0; z < 4; ++z)
#pragma unroll
            for (int g = 0; g < 4; ++g)
                acc[z][g] = __builtin_amdgcn_mfma_f32_16x16x32_bf16(
                    wf[z * 4 + g], xf[ks], acc[z][g], 0, 0, 0);
    }

    // ---- epilogue: acc already includes Uh; add bias, gates, nt stores ----
#pragma unroll
    for (int z = 0; z < 4; ++z) {
        const int kb = (w * 4 + z) * 16 + q * 4;
        const f4v bi  = *(const f4v*)&b_iou[kb];
        const f4v bo  = *(const f4v*)&b_iou[256 + kb];
        const f4v bu  = *(const f4v*)&b_iou[512 + kb];
        const f4v bf4 = *(const f4v*)&b_f[kb];
        const f4v ai = acc[z][0], ao = acc[z][1], au = acc[z][2], af = acc[z][3];
        const f4v fv = fcv[z];
        f4v cc, hh, ff;
        cc.x = fsig(ai.x + bi.x) * ftanh(au.x + bu.x) + fv.x;
        cc.y = fsig(ai.y + bi.y) * ftanh(au.y + bu.y) + fv.y;
        cc.z = fsig(ai.z + bi.z) * ftanh(au.z + bu.z) + fv.z;
        cc.w = fsig(ai.w + bi.w) * ftanh(au.w + bu.w) + fv.w;
        hh.x = fsig(ao.x + bo.x) * ftanh(cc.x);
        hh.y = fsig(ao.y + bo.y) * ftanh(cc.y);
        hh.z = fsig(ao.z + bo.z) * ftanh(cc.z);
        hh.w = fsig(ao.w + bo.w) * ftanh(cc.w);
        ff.x = af.x + bf4.x;
        ff.y = af.y + bf4.y;
        ff.z = af.z + bf4.z;
        ff.w = af.w + bf4.w;
        const size_t oidx = (size_t)n * 256 + kb;
        __builtin_nontemporal_store(hh, (f4v*)(out_h + oidx));
        __builtin_nontemporal_store(cc, (f4v*)(out_c + oidx));
        __builtin_nontemporal_store(ff, (f4v*)(out_f + oidx));
    }
}

extern "C" void kernel_launch(void* const* d_in, const int* in_sizes, int n_in,
                              void* d_out, int out_size, void* d_ws, size_t ws_size,
                              hipStream_t stream) {
    const float* x     = (const float*)d_in[0];
    const float* Uh    = (const float*)d_in[1];
    const float* fc    = (const float*)d_in[2];
    const float* W_iou = (const float*)d_in[3];
    const float* b_iou = (const float*)d_in[4];
    const float* W_f   = (const float*)d_in[5];
    const float* b_f   = (const float*)d_in[6];
    float* out = (float*)d_out;
    short* wpk = (short*)d_ws;

    if (ws_size >= 512 * 1024) {
        pack_w<<<128, 256, 0, stream>>>(W_iou, W_f, wpk);
        treelstm_main<true><<<GRID, 256, 0, stream>>>(x, Uh, fc, W_iou, b_iou,
                                                      W_f, b_f, wpk, out);
    } else {
        treelstm_main<false><<<GRID, 256, 0, stream>>>(x, Uh, fc, W_iou, b_iou,
                                                       W_f, b_f, wpk, out);
    }
}